// Round 19
// baseline (398.125 us; speedup 1.0000x reference)
//
#include <hip/hip_runtime.h>

#define T_   256
#define F_   32
#define NBB  16     // full 16-wide fragments
#define TPB  768    // 12 waves: 0-3 L1-MFMA, 4-5 L2-MFMA, 6-9 L1-comb/x, 10-11 L2-comb
#define IMW  104
#define XLW  40     // x-lo row pitch (ushorts, 80B, 16B-aligned)
#define PR1  260    // pre1 row stride (f32)
#define PR2  132

typedef __attribute__((ext_vector_type(8))) short bf16x8;
typedef __attribute__((ext_vector_type(4))) float f32x4;
typedef __attribute__((ext_vector_type(4))) unsigned short ush4;

#define K1f  (-1.44269504f)   // -log2(e)   : sigmoid gates
#define K2f  (-2.88539008f)   // -2*log2(e) : tanh gate & tanh(c)

__device__ __forceinline__ unsigned short bf16_rne(float x){
    unsigned u = __float_as_uint(x);
    u += 0x7FFF + ((u >> 16) & 1);
    return (unsigned short)(u >> 16);
}
__device__ __forceinline__ void bf16_split(float x, unsigned short& h, unsigned short& l){
    h = bf16_rne(x);
    float xr = __uint_as_float(((unsigned)h) << 16);
    l = bf16_rne(x - xr);
}
__device__ __forceinline__ void make_frags_s(const float* __restrict__ p8, float s,
                                             bf16x8& fh, bf16x8& fl){
    #pragma unroll
    for (int e = 0; e < 8; ++e){
        unsigned short h, l; bf16_split(s * p8[e], h, l);
        fh[e] = (short)h; fl[e] = (short)l;
    }
}
__device__ __forceinline__ float sigm_pre(float p){   // p = -log2e*x
    return __builtin_amdgcn_rcpf(1.f + __builtin_amdgcn_exp2f(p));
}
__device__ __forceinline__ float tanh_pre(float p){   // p = -2log2e*x
    return fmaf(2.f, __builtin_amdgcn_rcpf(1.f + __builtin_amdgcn_exp2f(p)), -1.f);
}
__device__ __forceinline__ float unit_combine(float gi, float gf, float gg, float go, float& c){
    const float i_ = sigm_pre(gi);
    const float f_ = sigm_pre(gf);
    const float g_ = tanh_pre(gg);
    const float o_ = sigm_pre(go);
    c = fmaf(f_, c, i_ * g_);
    return o_ * tanh_pre(K2f * c);
}

#define MFMA(A,B,C) __builtin_amdgcn_mfma_f32_16x16x32_bf16((A),(B),(C),0,0,0)

// LDS-visibility barrier WITHOUT vmcnt drain (x-loads stay in flight).
__device__ __forceinline__ void step_barrier(){
    asm volatile("s_waitcnt lgkmcnt(0)" ::: "memory");
    __builtin_amdgcn_s_barrier();
}

// (768,3): 3 waves/SIMD, reg cap ~170/wave. MFMA waves ~150 (96 AGPR weights).
__global__ __launch_bounds__(TPB, 3) void lstm_mfma(
    const float* __restrict__ x,      // [4096,256,32]
    const float* __restrict__ W_ih1,  // [256,32]
    const float* __restrict__ W_hh1,  // [256,64]
    const float* __restrict__ b_ih1,  // [256]
    const float* __restrict__ b_hh1,  // [256]
    const float* __restrict__ W_ih2,  // [128,64]
    const float* __restrict__ W_hh2,  // [128,32]
    const float* __restrict__ b_ih2,  // [128]
    const float* __restrict__ b_hh2,  // [128]
    const float* __restrict__ W_fc1,  // [16,32]
    const float* __restrict__ b_fc1,  // [16]
    const float* __restrict__ W_fc2,  // [1,16]
    const float* __restrict__ b_fc2,  // [1]
    float* __restrict__ out)          // [4096]
{
    const int tid  = threadIdx.x;
    const int lane = tid & 63;
    const int wid  = tid >> 6;        // 0..11
    const int bb   = lane & 15;       // fragment col = batch
    const int kg   = (lane >> 4) & 3; // k-group of 8
    const int b0   = blockIdx.x * NBB;

    __shared__ __align__(16) unsigned short i1h[2][NBB][IMW];   // [x(32)|h1(64)] hi
    __shared__ __align__(16) unsigned short x1l[2][NBB][XLW];   // x lo
    __shared__ __align__(16) unsigned short i2h[2][NBB][IMW];   // [h1(64)|h2(32)] hi
    __shared__ __align__(16) float pre1[NBB * PR1];
    __shared__ __align__(16) float pre2[NBB * PR2];
    __shared__ float hfin[NBB][32];
    __shared__ float hd[NBB][16];

    // ===== weight fragments: 4 tiles/wave on MFMA waves =====
    // L1 (wid 0-3): gate = wid, rowblocks 0..3 -> offs = 64*wid + 16*tt
    // L2 (wid 4-5): j = wid-4, tiles 4j+tt: gate 2j+(tt>>1) -> offs = 64*j + 16*tt
    bf16x8 wh[4][3], wl[4][3];
    f32x4  bfr[4];
    int    offs[4];
    if (wid < 4){
        const float s = (wid == 2) ? K2f : K1f;
        #pragma unroll
        for (int tt = 0; tt < 4; ++tt){
            offs[tt] = 64*wid + 16*tt;
            const int r = offs[tt] + bb;
            make_frags_s(&W_ih1[r*32 +      8*kg], s, wh[tt][0], wl[tt][0]);
            make_frags_s(&W_hh1[r*64 +      8*kg], s, wh[tt][1], wl[tt][1]);
            make_frags_s(&W_hh1[r*64 + 32 + 8*kg], s, wh[tt][2], wl[tt][2]);
            #pragma unroll
            for (int q = 0; q < 4; ++q){
                const int row = offs[tt] + 4*kg + q;
                bfr[tt][q] = s * (b_ih1[row] + b_hh1[row]);
            }
        }
    } else if (wid < 6){
        const int j = wid - 4;
        #pragma unroll
        for (int tt = 0; tt < 4; ++tt){
            const int g = 2*j + (tt >> 1);
            const float s = (g == 2) ? K2f : K1f;
            offs[tt] = 64*j + 16*tt;   // == 32*g + 16*(tt&1)
            const int r = offs[tt] + bb;
            make_frags_s(&W_ih2[r*64 +      8*kg], s, wh[tt][0], wl[tt][0]);
            make_frags_s(&W_ih2[r*64 + 32 + 8*kg], s, wh[tt][1], wl[tt][1]);
            make_frags_s(&W_hh2[r*32 +      8*kg], s, wh[tt][2], wl[tt][2]);
            #pragma unroll
            for (int q = 0; q < 4; ++q){
                const int row = offs[tt] + 4*kg + q;
                bfr[tt][q] = s * (b_ih2[row] + b_hh2[row]);
            }
        }
    }

    // ===== combine / x ownership =====
    // waves 6-9 (ct 0..255): L1-combine batch cb, units u0..u0+3; x floats xf,xf+1
    const int ct = tid - 384;
    const int cb = (ct >> 4) & 15;
    const int u0 = (ct & 15) * 4;
    float c1[4] = {0.f, 0.f, 0.f, 0.f};
    const int xf = (ct & 15) * 2;
    const size_t xbase = (size_t)(b0 + cb) * (T_*F_) + xf;
    float2 xc = make_float2(0.f, 0.f);
    // waves 10-11 (c2t 0..127): L2-combine batch cb2, units v0..v0+3
    const int c2t = tid - 640;
    const int cb2 = (c2t >> 3) & 15;
    const int v0  = (c2t & 7) * 4;
    float c2[4] = {0.f, 0.f, 0.f, 0.f};

    // ===== init: zero images, stage x(0), preload x(1) =====
    for (int i = tid; i < 2*NBB*IMW; i += TPB){
        (&i1h[0][0][0])[i] = 0; (&i2h[0][0][0])[i] = 0;
    }
    for (int i = tid; i < 2*NBB*XLW; i += TPB) (&x1l[0][0][0])[i] = 0;
    __syncthreads();
    if (wid >= 6 && wid < 10){
        float2 x0 = *(const float2*)&x[xbase];
        unsigned short h0h, h0l, h1h, h1l;
        bf16_split(x0.x, h0h, h0l); bf16_split(x0.y, h1h, h1l);
        *(unsigned*)&i1h[0][cb][xf] = (unsigned)h0h | ((unsigned)h1h << 16);
        *(unsigned*)&x1l[0][cb][xf] = (unsigned)h0l | ((unsigned)h1l << 16);
        xc = *(const float2*)&x[xbase + F_];
    }
    __syncthreads();

    // ===== main loop (r18 schedule, consolidated roles) =====
    // P1(t): L1-MFMA(t)->pre1 [w0-3] | L2-comb(t-2)->i2h[nxt] [w10-11] | x(t+1) [w6-9]
    // P2(t): L2-MFMA(t-1)->pre2 [w4-5] | L1-comb(t)->i1h[nxt],i2h[cur] [w6-9]
    for (int t = 0; t <= T_ + 1; ++t){
        const int cur = t & 1, nxt = cur ^ 1;

        // ---------- P1 ----------
        if (wid < 4){
            if (t < T_){
                const unsigned short* ph = &i1h[cur][0][0] + bb*IMW + 8*kg;
                bf16x8 vh[3];
                #pragma unroll
                for (int kb = 0; kb < 3; ++kb)
                    vh[kb] = *(const bf16x8*)(ph + 32*kb);
                const bf16x8 vl0 = *(const bf16x8*)&x1l[cur][bb][8*kg];
                __builtin_amdgcn_s_setprio(1);
                f32x4 a0 = bfr[0], a1 = bfr[1], a2 = bfr[2], a3 = bfr[3];
                #pragma unroll
                for (int kb = 0; kb < 3; ++kb){
                    a0 = MFMA(wh[0][kb], vh[kb], a0);
                    a1 = MFMA(wh[1][kb], vh[kb], a1);
                    a2 = MFMA(wh[2][kb], vh[kb], a2);
                    a3 = MFMA(wh[3][kb], vh[kb], a3);
                }
                #pragma unroll
                for (int kb = 0; kb < 3; ++kb){
                    a0 = MFMA(wl[0][kb], vh[kb], a0);
                    a1 = MFMA(wl[1][kb], vh[kb], a1);
                    a2 = MFMA(wl[2][kb], vh[kb], a2);
                    a3 = MFMA(wl[3][kb], vh[kb], a3);
                }
                a0 = MFMA(wh[0][0], vl0, a0);   // x-lo (k 0..31 only)
                a1 = MFMA(wh[1][0], vl0, a1);
                a2 = MFMA(wh[2][0], vl0, a2);
                a3 = MFMA(wh[3][0], vl0, a3);
                __builtin_amdgcn_s_setprio(0);
                *(f32x4*)&pre1[bb*PR1 + offs[0] + 4*kg] = a0;
                *(f32x4*)&pre1[bb*PR1 + offs[1] + 4*kg] = a1;
                *(f32x4*)&pre1[bb*PR1 + offs[2] + 4*kg] = a2;
                *(f32x4*)&pre1[bb*PR1 + offs[3] + 4*kg] = a3;
            }
        } else if (wid >= 10){
            const int m = t - 2;
            if (m >= 0 && m < T_){
                const float* p = &pre2[cb2*PR2];
                const f32x4 gi = *(const f32x4*)&p[     v0];
                const f32x4 gf = *(const f32x4*)&p[32 + v0];
                const f32x4 gg = *(const f32x4*)&p[64 + v0];
                const f32x4 go = *(const f32x4*)&p[96 + v0];
                ush4 HH;
                float hv[4];
                #pragma unroll
                for (int q = 0; q < 4; ++q){
                    hv[q] = unit_combine(gi[q], gf[q], gg[q], go[q], c2[q]);
                    HH[q] = bf16_rne(hv[q]);
                }
                *(ush4*)&i2h[nxt][cb2][64 + v0] = HH;
                if (m == T_ - 1){
                    *(f32x4*)&hfin[cb2][v0] = *(f32x4*)hv;
                }
            }
        } else if (wid >= 6){
            if (t + 1 < T_){
                unsigned short h0h, h0l, h1h, h1l;
                bf16_split(xc.x, h0h, h0l); bf16_split(xc.y, h1h, h1l);
                *(unsigned*)&i1h[nxt][cb][xf] = (unsigned)h0h | ((unsigned)h1h << 16);
                *(unsigned*)&x1l[nxt][cb][xf] = (unsigned)h0l | ((unsigned)h1l << 16);
                const int tn = (t + 2 < T_) ? t + 2 : T_ - 1;
                xc = *(const float2*)&x[xbase + (size_t)tn * F_];
            }
        }
        step_barrier();

        // ---------- P2 ----------
        if (wid >= 4 && wid < 6){
            const int k = t - 1;
            if (k >= 0 && k < T_){
                // i2h[nxt] = [h1(k) | h2(k-1)]
                const unsigned short* ph = &i2h[nxt][0][0] + bb*IMW + 8*kg;
                bf16x8 vh[3];
                #pragma unroll
                for (int kb = 0; kb < 3; ++kb)
                    vh[kb] = *(const bf16x8*)(ph + 32*kb);
                __builtin_amdgcn_s_setprio(1);
                f32x4 a0 = bfr[0], a1 = bfr[1], a2 = bfr[2], a3 = bfr[3];
                #pragma unroll
                for (int kb = 0; kb < 3; ++kb){
                    a0 = MFMA(wh[0][kb], vh[kb], a0);
                    a1 = MFMA(wh[1][kb], vh[kb], a1);
                    a2 = MFMA(wh[2][kb], vh[kb], a2);
                    a3 = MFMA(wh[3][kb], vh[kb], a3);
                }
                #pragma unroll
                for (int kb = 0; kb < 3; ++kb){
                    a0 = MFMA(wl[0][kb], vh[kb], a0);
                    a1 = MFMA(wl[1][kb], vh[kb], a1);
                    a2 = MFMA(wl[2][kb], vh[kb], a2);
                    a3 = MFMA(wl[3][kb], vh[kb], a3);
                }
                __builtin_amdgcn_s_setprio(0);
                *(f32x4*)&pre2[bb*PR2 + offs[0] + 4*kg] = a0;
                *(f32x4*)&pre2[bb*PR2 + offs[1] + 4*kg] = a1;
                *(f32x4*)&pre2[bb*PR2 + offs[2] + 4*kg] = a2;
                *(f32x4*)&pre2[bb*PR2 + offs[3] + 4*kg] = a3;
            }
        } else if (wid >= 6 && wid < 10){
            if (t < T_){
                const float* p = &pre1[cb*PR1];
                const f32x4 gi = *(const f32x4*)&p[      u0];
                const f32x4 gf = *(const f32x4*)&p[ 64 + u0];
                const f32x4 gg = *(const f32x4*)&p[128 + u0];
                const f32x4 go = *(const f32x4*)&p[192 + u0];
                ush4 HH;
                #pragma unroll
                for (int q = 0; q < 4; ++q){
                    const float h = unit_combine(gi[q], gf[q], gg[q], go[q], c1[q]);
                    HH[q] = bf16_rne(h);
                }
                *(ush4*)&i1h[nxt][cb][32 + u0] = HH;   // h1(t) for L1-MFMA(t+1)
                *(ush4*)&i2h[cur][cb][u0]      = HH;   // h1(t) for L2-MFMA(t)
            }
        }
        step_barrier();
    }

    __syncthreads();
    // ===== head: fc1(16)+relu, fc2(1) =====
    if (tid < NBB * 16){
        const int b = tid >> 4, j2 = tid & 15;
        float a = b_fc1[j2];
        #pragma unroll
        for (int kk = 0; kk < 32; ++kk) a = fmaf(W_fc1[j2*32 + kk], hfin[b][kk], a);
        hd[b][j2] = fmaxf(a, 0.f);
    }
    __syncthreads();
    if (tid < NBB){
        float a = b_fc2[0];
        #pragma unroll
        for (int kk = 0; kk < 16; ++kk) a = fmaf(W_fc2[kk], hd[tid][kk], a);
        out[b0 + tid] = a;
    }
}

extern "C" void kernel_launch(void* const* d_in, const int* in_sizes, int n_in,
                              void* d_out, int out_size, void* d_ws, size_t ws_size,
                              hipStream_t stream) {
    const float* x     = (const float*)d_in[0];
    const float* W_ih1 = (const float*)d_in[1];
    const float* W_hh1 = (const float*)d_in[2];
    const float* b_ih1 = (const float*)d_in[3];
    const float* b_hh1 = (const float*)d_in[4];
    const float* W_ih2 = (const float*)d_in[5];
    const float* W_hh2 = (const float*)d_in[6];
    const float* b_ih2 = (const float*)d_in[7];
    const float* b_hh2 = (const float*)d_in[8];
    const float* W_fc1 = (const float*)d_in[9];
    const float* b_fc1 = (const float*)d_in[10];
    const float* W_fc2 = (const float*)d_in[11];
    const float* b_fc2 = (const float*)d_in[12];
    float* out = (float*)d_out;

    const int B = in_sizes[0] / (T_ * F_);   // 4096
    dim3 grid(B / NBB), block(TPB);          // 256 blocks, 1/CU, 12 waves
    hipLaunchKernelGGL(lstm_mfma, grid, block, 0, stream,
                       x, W_ih1, W_hh1, b_ih1, b_hh1,
                       W_ih2, W_hh2, b_ih2, b_hh2,
                       W_fc1, b_fc1, W_fc2, b_fc2, out);
}

// Round 20
// 252.949 us; speedup vs baseline: 1.5739x; 1.5739x over previous
//
#include <hip/hip_runtime.h>

#define T_   256
#define F_   32
#define NBB  16     // full 16-wide fragments
#define TPB  1024   // 16 waves: 0-7 L1-role (2 tiles), 8-15 L2-role (1 tile)
#define IMW  104
#define XLW  40     // x-lo row pitch (ushorts, 80B, 16B-aligned)
#define PR1  260    // pre1 row stride (f32)
#define PR2  132

typedef __attribute__((ext_vector_type(8))) short bf16x8;
typedef __attribute__((ext_vector_type(4))) float f32x4;

#define K1f  (-1.44269504f)   // -log2(e)   : sigmoid gates
#define K2f  (-2.88539008f)   // -2*log2(e) : tanh gate & tanh(c)

__device__ __forceinline__ unsigned short bf16_rne(float x){
    unsigned u = __float_as_uint(x);
    u += 0x7FFF + ((u >> 16) & 1);
    return (unsigned short)(u >> 16);
}
__device__ __forceinline__ void bf16_split(float x, unsigned short& h, unsigned short& l){
    h = bf16_rne(x);
    float xr = __uint_as_float(((unsigned)h) << 16);
    l = bf16_rne(x - xr);
}
__device__ __forceinline__ void make_frags_s(const float* __restrict__ p8, float s,
                                             bf16x8& fh, bf16x8& fl){
    #pragma unroll
    for (int e = 0; e < 8; ++e){
        unsigned short h, l; bf16_split(s * p8[e], h, l);
        fh[e] = (short)h; fl[e] = (short)l;
    }
}
__device__ __forceinline__ float sigm_pre(float p){   // p = -log2e*x
    return __builtin_amdgcn_rcpf(1.f + __builtin_amdgcn_exp2f(p));
}
__device__ __forceinline__ float tanh_pre(float p){   // p = -2log2e*x
    return fmaf(2.f, __builtin_amdgcn_rcpf(1.f + __builtin_amdgcn_exp2f(p)), -1.f);
}
__device__ __forceinline__ float unit_combine(float gi, float gf, float gg, float go, float& c){
    const float i_ = sigm_pre(gi);
    const float f_ = sigm_pre(gf);
    const float g_ = tanh_pre(gg);
    const float o_ = sigm_pre(go);
    c = fmaf(f_, c, i_ * g_);
    return o_ * tanh_pre(K2f * c);
}

#define MFMA(A,B,C) __builtin_amdgcn_mfma_f32_16x16x32_bf16((A),(B),(C),0,0,0)

// LDS-visibility barrier WITHOUT vmcnt drain (x-loads stay in flight).
__device__ __forceinline__ void step_barrier(){
    asm volatile("s_waitcnt lgkmcnt(0)" ::: "memory");
    __builtin_amdgcn_s_barrier();
}

// waves_per_eu(4,4): pins 4 waves/SIMD -> 128-reg cap AND forbids the
// allocator's 64-reg 2-block heuristic (r10 failure). 2-tile rule (r19
// lesson): L1 waves carry 12 bf16x8 weights (AGPR), L2 waves 6.
__global__ __launch_bounds__(TPB) __attribute__((amdgpu_waves_per_eu(4, 4)))
void lstm_mfma(
    const float* __restrict__ x,      // [4096,256,32]
    const float* __restrict__ W_ih1,  // [256,32]
    const float* __restrict__ W_hh1,  // [256,64]
    const float* __restrict__ b_ih1,  // [256]
    const float* __restrict__ b_hh1,  // [256]
    const float* __restrict__ W_ih2,  // [128,64]
    const float* __restrict__ W_hh2,  // [128,32]
    const float* __restrict__ b_ih2,  // [128]
    const float* __restrict__ b_hh2,  // [128]
    const float* __restrict__ W_fc1,  // [16,32]
    const float* __restrict__ b_fc1,  // [16]
    const float* __restrict__ W_fc2,  // [1,16]
    const float* __restrict__ b_fc2,  // [1]
    float* __restrict__ out)          // [4096]
{
    const int tid  = threadIdx.x;
    const int lane = tid & 63;
    const int wid  = tid >> 6;        // 0..15
    const int bb   = lane & 15;       // fragment col = batch
    const int kg   = (lane >> 4) & 3; // k-group of 8
    const int b0   = blockIdx.x * NBB;

    __shared__ __align__(16) unsigned short i1h[2][NBB][IMW];   // [x(32)|h1(64)] hi
    __shared__ __align__(16) unsigned short x1l[2][NBB][XLW];   // x lo
    __shared__ __align__(16) unsigned short i2h[2][NBB][IMW];   // [h1(64)|h2(32)] hi
    __shared__ __align__(16) float pre1[NBB * PR1];
    __shared__ __align__(16) float pre2[NBB * PR2];
    __shared__ float hfin[NBB][32];
    __shared__ float hd[NBB][16];

    // ===== weight fragments =====
    // L1 (wid 0-7): tiles 2w,2w+1; tile T: gate T>>2, rowblock T&3
    // L2 (wid 8-15): tile j=wid-8; gate j>>1, rowblock j&1
    bf16x8 wh[2][3], wl[2][3];
    f32x4  bfr[2];
    int    offs[2];
    if (wid < 8){
        #pragma unroll
        for (int tt = 0; tt < 2; ++tt){
            const int Tt = 2*wid + tt;
            const int g = Tt >> 2, rb = Tt & 3;
            const float s = (g == 2) ? K2f : K1f;
            offs[tt] = 64*g + 16*rb;
            const int r = offs[tt] + bb;
            make_frags_s(&W_ih1[r*32 +      8*kg], s, wh[tt][0], wl[tt][0]);
            make_frags_s(&W_hh1[r*64 +      8*kg], s, wh[tt][1], wl[tt][1]);
            make_frags_s(&W_hh1[r*64 + 32 + 8*kg], s, wh[tt][2], wl[tt][2]);
            #pragma unroll
            for (int q = 0; q < 4; ++q){
                const int row = offs[tt] + 4*kg + q;
                bfr[tt][q] = s * (b_ih1[row] + b_hh1[row]);
            }
        }
    } else {
        const int j = wid - 8;
        const int g = j >> 1;
        const float s = (g == 2) ? K2f : K1f;
        offs[0] = 32*g + 16*(j & 1);
        const int r = offs[0] + bb;
        make_frags_s(&W_ih2[r*64 +      8*kg], s, wh[0][0], wl[0][0]);
        make_frags_s(&W_ih2[r*64 + 32 + 8*kg], s, wh[0][1], wl[0][1]);
        make_frags_s(&W_hh2[r*32 +      8*kg], s, wh[0][2], wl[0][2]);
        #pragma unroll
        for (int q = 0; q < 4; ++q){
            const int row = offs[0] + 4*kg + q;
            bfr[0][q] = s * (b_ih2[row] + b_hh2[row]);
        }
    }

    // ===== combine / x ownership =====
    // L1-combine (tid<512, P2): batch cb=tid>>5, units u0,u0+1 (r16 float2 map)
    const int cb = tid >> 5;
    const int u0 = (tid & 31) * 2;
    float c1a = 0.f, c1b = 0.f;
    // L2-combine + x (tid>=512, P1): xi=tid-512: batch cb2=xi>>5, unit v=xi&31
    const int xi  = tid & 511;
    const int cb2 = xi >> 5;
    const int v   = xi & 31;
    float c2 = 0.f;
    const size_t xbase = (size_t)(b0 + cb2) * (T_*F_) + v;
    float xc = 0.f;

    // ===== init: zero images, stage x(0), preload x(1) =====
    for (int i = tid; i < 2*NBB*IMW; i += TPB){
        (&i1h[0][0][0])[i] = 0; (&i2h[0][0][0])[i] = 0;
    }
    for (int i = tid; i < 2*NBB*XLW; i += TPB) (&x1l[0][0][0])[i] = 0;
    __syncthreads();
    if (wid >= 8){
        unsigned short hh, hl;
        bf16_split(x[xbase], hh, hl);
        i1h[0][cb2][v] = hh; x1l[0][cb2][v] = hl;
        xc = x[xbase + F_];
    }
    __syncthreads();

    // ===== main loop (r18 schedule, 16 waves) =====
    // P1(t): L1-MFMA(t)->pre1 [w0-7] | L2-comb(t-2)->i2h[nxt] + x(t+1) [w8-15]
    // P2(t): L1-comb(t)->i1h[nxt],i2h[cur] [w0-7] | L2-MFMA(t-1)->pre2 [w8-15]
    for (int t = 0; t <= T_ + 1; ++t){
        const int cur = t & 1, nxt = cur ^ 1;

        // ---------- P1 ----------
        if (wid < 8){
            if (t < T_){
                const unsigned short* ph = &i1h[cur][0][0] + bb*IMW + 8*kg;
                bf16x8 vh[3];
                #pragma unroll
                for (int kb = 0; kb < 3; ++kb)
                    vh[kb] = *(const bf16x8*)(ph + 32*kb);
                const bf16x8 vl0 = *(const bf16x8*)&x1l[cur][bb][8*kg];
                __builtin_amdgcn_s_setprio(1);
                f32x4 a0 = bfr[0], a1 = bfr[1];
                #pragma unroll
                for (int kb = 0; kb < 3; ++kb){
                    a0 = MFMA(wh[0][kb], vh[kb], a0);
                    a1 = MFMA(wh[1][kb], vh[kb], a1);
                }
                #pragma unroll
                for (int kb = 0; kb < 3; ++kb){
                    a0 = MFMA(wl[0][kb], vh[kb], a0);
                    a1 = MFMA(wl[1][kb], vh[kb], a1);
                }
                a0 = MFMA(wh[0][0], vl0, a0);   // x-lo (k 0..31 only)
                a1 = MFMA(wh[1][0], vl0, a1);
                __builtin_amdgcn_s_setprio(0);
                *(f32x4*)&pre1[bb*PR1 + offs[0] + 4*kg] = a0;
                *(f32x4*)&pre1[bb*PR1 + offs[1] + 4*kg] = a1;
            }
        } else {
            const int m = t - 2;
            if (m >= 0 && m < T_){
                const float* p = &pre2[cb2*PR2];
                const float h2 = unit_combine(p[v], p[32 + v], p[64 + v], p[96 + v], c2);
                i2h[nxt][cb2][64 + v] = bf16_rne(h2);
                if (m == T_ - 1) hfin[cb2][v] = h2;
            }
            if (t + 1 < T_){
                unsigned short hh, hl;
                bf16_split(xc, hh, hl);
                i1h[nxt][cb2][v] = hh; x1l[nxt][cb2][v] = hl;
                const int tn = (t + 2 < T_) ? t + 2 : T_ - 1;
                xc = x[xbase + (size_t)tn * F_];
            }
        }
        step_barrier();

        // ---------- P2 ----------
        if (wid < 8){
            if (t < T_){
                const float* p = &pre1[cb*PR1];
                const float2 gi = *(const float2*)&p[      u0];
                const float2 gf = *(const float2*)&p[ 64 + u0];
                const float2 gg = *(const float2*)&p[128 + u0];
                const float2 go = *(const float2*)&p[192 + u0];
                const float h0 = unit_combine(gi.x, gf.x, gg.x, go.x, c1a);
                const float h1 = unit_combine(gi.y, gf.y, gg.y, go.y, c1b);
                const unsigned wh_ =
                    (unsigned)bf16_rne(h0) | ((unsigned)bf16_rne(h1) << 16);
                *(unsigned*)&i1h[nxt][cb][32 + u0] = wh_;   // h1(t) for L1-MFMA(t+1)
                *(unsigned*)&i2h[cur][cb][u0]      = wh_;   // h1(t) for L2-MFMA(t)
            }
        } else {
            const int k = t - 1;
            if (k >= 0 && k < T_){
                // i2h[nxt] = [h1(k) | h2(k-1)]
                const unsigned short* ph = &i2h[nxt][0][0] + bb*IMW + 8*kg;
                bf16x8 vh[3];
                #pragma unroll
                for (int kb = 0; kb < 3; ++kb)
                    vh[kb] = *(const bf16x8*)(ph + 32*kb);
                __builtin_amdgcn_s_setprio(1);
                f32x4 a0 = bfr[0];
                #pragma unroll
                for (int kb = 0; kb < 3; ++kb) a0 = MFMA(wh[0][kb], vh[kb], a0);
                #pragma unroll
                for (int kb = 0; kb < 3; ++kb) a0 = MFMA(wl[0][kb], vh[kb], a0);
                __builtin_amdgcn_s_setprio(0);
                *(f32x4*)&pre2[bb*PR2 + offs[0] + 4*kg] = a0;
            }
        }
        step_barrier();
    }

    __syncthreads();
    // ===== head: fc1(16)+relu, fc2(1) =====
    if (tid < NBB * 16){
        const int b = tid >> 4, j2 = tid & 15;
        float a = b_fc1[j2];
        #pragma unroll
        for (int kk = 0; kk < 32; ++kk) a = fmaf(W_fc1[j2*32 + kk], hfin[b][kk], a);
        hd[b][j2] = fmaxf(a, 0.f);
    }
    __syncthreads();
    if (tid < NBB){
        float a = b_fc2[0];
        #pragma unroll
        for (int kk = 0; kk < 16; ++kk) a = fmaf(W_fc2[kk], hd[tid][kk], a);
        out[b0 + tid] = a;
    }
}

extern "C" void kernel_launch(void* const* d_in, const int* in_sizes, int n_in,
                              void* d_out, int out_size, void* d_ws, size_t ws_size,
                              hipStream_t stream) {
    const float* x     = (const float*)d_in[0];
    const float* W_ih1 = (const float*)d_in[1];
    const float* W_hh1 = (const float*)d_in[2];
    const float* b_ih1 = (const float*)d_in[3];
    const float* b_hh1 = (const float*)d_in[4];
    const float* W_ih2 = (const float*)d_in[5];
    const float* W_hh2 = (const float*)d_in[6];
    const float* b_ih2 = (const float*)d_in[7];
    const float* b_hh2 = (const float*)d_in[8];
    const float* W_fc1 = (const float*)d_in[9];
    const float* b_fc1 = (const float*)d_in[10];
    const float* W_fc2 = (const float*)d_in[11];
    const float* b_fc2 = (const float*)d_in[12];
    float* out = (float*)d_out;

    const int B = in_sizes[0] / (T_ * F_);   // 4096
    dim3 grid(B / NBB), block(TPB);          // 256 blocks, 1/CU, 16 waves
    hipLaunchKernelGGL(lstm_mfma, grid, block, 0, stream,
                       x, W_ih1, W_hh1, b_ih1, b_hh1,
                       W_ih2, W_hh2, b_ih2, b_hh2,
                       W_fc1, b_fc1, W_fc2, b_fc2, out);
}

// Round 21
// 251.373 us; speedup vs baseline: 1.5838x; 1.0063x over previous
//
#include <hip/hip_runtime.h>

#define T_   256
#define F_   32
#define NBB  16     // full 16-wide fragments
#define TPB  768    // 12 waves: 0-7 L1-role, 8-11 L2-role
#define IMW  104
#define XLW  40     // x-lo row pitch (ushorts, 80B, 16B-aligned)
#define PR1  260    // pre1 row stride (f32)
#define PR2  132

typedef __attribute__((ext_vector_type(8))) short bf16x8;
typedef __attribute__((ext_vector_type(4))) float f32x4;
typedef __attribute__((ext_vector_type(4))) unsigned short ush4;

#define K1f  (-1.44269504f)   // -log2(e)   : sigmoid gates
#define K2f  (-2.88539008f)   // -2*log2(e) : tanh gate & tanh(c)

__device__ __forceinline__ unsigned short bf16_rne(float x){
    unsigned u = __float_as_uint(x);
    u += 0x7FFF + ((u >> 16) & 1);
    return (unsigned short)(u >> 16);
}
__device__ __forceinline__ void bf16_split(float x, unsigned short& h, unsigned short& l){
    h = bf16_rne(x);
    float xr = __uint_as_float(((unsigned)h) << 16);
    l = bf16_rne(x - xr);
}
__device__ __forceinline__ void make_frags_s(const float* __restrict__ p8, float s,
                                             bf16x8& fh, bf16x8& fl){
    #pragma unroll
    for (int e = 0; e < 8; ++e){
        unsigned short h, l; bf16_split(s * p8[e], h, l);
        fh[e] = (short)h; fl[e] = (short)l;
    }
}
__device__ __forceinline__ float sigm_pre(float p){   // p = -log2e*x
    return __builtin_amdgcn_rcpf(1.f + __builtin_amdgcn_exp2f(p));
}
__device__ __forceinline__ float tanh_pre(float p){   // p = -2log2e*x
    return fmaf(2.f, __builtin_amdgcn_rcpf(1.f + __builtin_amdgcn_exp2f(p)), -1.f);
}
__device__ __forceinline__ float unit_combine(float gi, float gf, float gg, float go, float& c){
    const float i_ = sigm_pre(gi);
    const float f_ = sigm_pre(gf);
    const float g_ = tanh_pre(gg);
    const float o_ = sigm_pre(go);
    c = fmaf(f_, c, i_ * g_);
    return o_ * tanh_pre(K2f * c);
}

#define MFMA(A,B,C) __builtin_amdgcn_mfma_f32_16x16x32_bf16((A),(B),(C),0,0,0)

// LDS-visibility barrier WITHOUT vmcnt drain (x-loads stay in flight).
__device__ __forceinline__ void step_barrier(){
    asm volatile("s_waitcnt lgkmcnt(0)" ::: "memory");
    __builtin_amdgcn_s_barrier();
}

// (768,3): r18's proven envelope (VGPR~68 + AGPR weights, no spill).
__global__ __launch_bounds__(TPB, 3) void lstm_mfma(
    const float* __restrict__ x,      // [4096,256,32]
    const float* __restrict__ W_ih1,  // [256,32]
    const float* __restrict__ W_hh1,  // [256,64]
    const float* __restrict__ b_ih1,  // [256]
    const float* __restrict__ b_hh1,  // [256]
    const float* __restrict__ W_ih2,  // [128,64]
    const float* __restrict__ W_hh2,  // [128,32]
    const float* __restrict__ b_ih2,  // [128]
    const float* __restrict__ b_hh2,  // [128]
    const float* __restrict__ W_fc1,  // [16,32]
    const float* __restrict__ b_fc1,  // [16]
    const float* __restrict__ W_fc2,  // [1,16]
    const float* __restrict__ b_fc2,  // [1]
    float* __restrict__ out)          // [4096]
{
    const int tid  = threadIdx.x;
    const int lane = tid & 63;
    const int wid  = tid >> 6;        // 0..11
    const int bb   = lane & 15;       // fragment col = batch
    const int kg   = (lane >> 4) & 3; // k-group of 8
    const int b0   = blockIdx.x * NBB;

    __shared__ __align__(16) unsigned short i1h[2][NBB][IMW];   // [x(32)|h1(64)] hi
    __shared__ __align__(16) unsigned short x1l[2][NBB][XLW];   // x lo
    __shared__ __align__(16) unsigned short i2h[2][NBB][IMW];   // [h1(64)|h2(32)] hi
    __shared__ __align__(16) float pre1[NBB * PR1];
    __shared__ __align__(16) float pre2[NBB * PR2];
    __shared__ float hfin[NBB][32];
    __shared__ float hd[NBB][16];

    // ===== weight fragments: 2 tiles/wave (hi+lo, pre-scaled) — r18 =====
    bf16x8 wh[2][3], wl[2][3];
    f32x4  bfr[2];
    int    offs[2];
    if (wid < 8){
        #pragma unroll
        for (int tt = 0; tt < 2; ++tt){
            const int Tt = 2*wid + tt;
            const int g = Tt >> 2, rb = Tt & 3;
            const float s = (g == 2) ? K2f : K1f;
            offs[tt] = 64*g + 16*rb;
            const int r = offs[tt] + bb;
            make_frags_s(&W_ih1[r*32 +      8*kg], s, wh[tt][0], wl[tt][0]);
            make_frags_s(&W_hh1[r*64 +      8*kg], s, wh[tt][1], wl[tt][1]);
            make_frags_s(&W_hh1[r*64 + 32 + 8*kg], s, wh[tt][2], wl[tt][2]);
            #pragma unroll
            for (int q = 0; q < 4; ++q){
                const int row = offs[tt] + 4*kg + q;
                bfr[tt][q] = s * (b_ih1[row] + b_hh1[row]);
            }
        }
    } else {
        const int j = wid - 8;
        #pragma unroll
        for (int tt = 0; tt < 2; ++tt){
            const int St = 2*j + tt;
            const int g = St >> 1, rb = St & 1;
            const float s = (g == 2) ? K2f : K1f;
            offs[tt] = 32*g + 16*rb;
            const int r = offs[tt] + bb;
            make_frags_s(&W_ih2[r*64 +      8*kg], s, wh[tt][0], wl[tt][0]);
            make_frags_s(&W_ih2[r*64 + 32 + 8*kg], s, wh[tt][1], wl[tt][1]);
            make_frags_s(&W_hh2[r*32 +      8*kg], s, wh[tt][2], wl[tt][2]);
            #pragma unroll
            for (int q = 0; q < 4; ++q){
                const int row = offs[tt] + 4*kg + q;
                bfr[tt][q] = s * (b_ih2[row] + b_hh2[row]);
            }
        }
    }

    // ===== combine / x ownership: f32x4 conflict-free mappings (r13 evidence) =====
    // L1-combine (tid<256, waves 0-3, P2): batch cb=tid>>4, units u0..u0+3
    const int cb = tid >> 4;            // valid for tid<256
    const int u0 = (tid & 15) * 4;
    float c1[4] = {0.f, 0.f, 0.f, 0.f};
    // L2-combine (waves 8-9, P1): c2t = tid-512 in 0..127: batch c2t>>3, units (c2t&7)*4
    const int c2t = tid & 127;
    const int cb2 = c2t >> 3;
    const int v0  = (c2t & 7) * 4;
    float c2[4] = {0.f, 0.f, 0.f, 0.f};
    // x-staging (waves 10-11, P1): xt = tid-640 in 0..127: batch xt>>3, floats (xt&7)*4
    const int xt  = tid & 127;
    const int xcb = xt >> 3;
    const int xf  = (xt & 7) * 4;
    const size_t xbase = (size_t)(b0 + xcb) * (T_*F_) + xf;
    float4 xc = make_float4(0.f, 0.f, 0.f, 0.f);

    // ===== init: zero images, stage x(0), preload x(1) =====
    for (int i = tid; i < 2*NBB*IMW; i += TPB){
        (&i1h[0][0][0])[i] = 0; (&i2h[0][0][0])[i] = 0;
    }
    for (int i = tid; i < 2*NBB*XLW; i += TPB) (&x1l[0][0][0])[i] = 0;
    __syncthreads();
    if (wid >= 10){
        float4 x0 = *(const float4*)&x[xbase];
        ush4 HH, HL;
        unsigned short h, l;
        bf16_split(x0.x, h, l); HH[0]=h; HL[0]=l;
        bf16_split(x0.y, h, l); HH[1]=h; HL[1]=l;
        bf16_split(x0.z, h, l); HH[2]=h; HL[2]=l;
        bf16_split(x0.w, h, l); HH[3]=h; HL[3]=l;
        *(ush4*)&i1h[0][xcb][xf] = HH;
        *(ush4*)&x1l[0][xcb][xf] = HL;
        xc = *(const float4*)&x[xbase + F_];
    }
    __syncthreads();

    // ===== main loop (r18 schedule, conflict-free combine maps) =====
    // P1(t): L1-MFMA(t)->pre1 [w0-7] | L2-comb(t-2)->i2h[nxt] [w8-9] | x(t+1) [w10-11]
    // P2(t): L1-comb(t)->i1h[nxt],i2h[cur] [w0-3] | L2-MFMA(t-1)->pre2 [w8-11]
    for (int t = 0; t <= T_ + 1; ++t){
        const int cur = t & 1, nxt = cur ^ 1;

        // ---------- P1 ----------
        if (wid < 8){
            if (t < T_){
                const unsigned short* ph = &i1h[cur][0][0] + bb*IMW + 8*kg;
                bf16x8 vh[3];
                #pragma unroll
                for (int kb = 0; kb < 3; ++kb)
                    vh[kb] = *(const bf16x8*)(ph + 32*kb);
                const bf16x8 vl0 = *(const bf16x8*)&x1l[cur][bb][8*kg];
                __builtin_amdgcn_s_setprio(1);
                f32x4 a0 = bfr[0], a1 = bfr[1];
                #pragma unroll
                for (int kb = 0; kb < 3; ++kb){
                    a0 = MFMA(wh[0][kb], vh[kb], a0);
                    a1 = MFMA(wh[1][kb], vh[kb], a1);
                }
                #pragma unroll
                for (int kb = 0; kb < 3; ++kb){
                    a0 = MFMA(wl[0][kb], vh[kb], a0);
                    a1 = MFMA(wl[1][kb], vh[kb], a1);
                }
                a0 = MFMA(wh[0][0], vl0, a0);   // x-lo (k 0..31 only)
                a1 = MFMA(wh[1][0], vl0, a1);
                __builtin_amdgcn_s_setprio(0);
                *(f32x4*)&pre1[bb*PR1 + offs[0] + 4*kg] = a0;
                *(f32x4*)&pre1[bb*PR1 + offs[1] + 4*kg] = a1;
            }
        } else if (wid < 10){
            const int m = t - 2;
            if (m >= 0 && m < T_){
                const float* p = &pre2[cb2*PR2];
                const f32x4 gi = *(const f32x4*)&p[     v0];
                const f32x4 gf = *(const f32x4*)&p[32 + v0];
                const f32x4 gg = *(const f32x4*)&p[64 + v0];
                const f32x4 go = *(const f32x4*)&p[96 + v0];
                ush4 HH;
                float hv[4];
                #pragma unroll
                for (int q = 0; q < 4; ++q){
                    hv[q] = unit_combine(gi[q], gf[q], gg[q], go[q], c2[q]);
                    HH[q] = bf16_rne(hv[q]);
                }
                *(ush4*)&i2h[nxt][cb2][64 + v0] = HH;
                if (m == T_ - 1){
                    hfin[cb2][v0]   = hv[0]; hfin[cb2][v0+1] = hv[1];
                    hfin[cb2][v0+2] = hv[2]; hfin[cb2][v0+3] = hv[3];
                }
            }
        } else {
            if (t + 1 < T_){
                ush4 HH, HL;
                unsigned short h, l;
                bf16_split(xc.x, h, l); HH[0]=h; HL[0]=l;
                bf16_split(xc.y, h, l); HH[1]=h; HL[1]=l;
                bf16_split(xc.z, h, l); HH[2]=h; HL[2]=l;
                bf16_split(xc.w, h, l); HH[3]=h; HL[3]=l;
                *(ush4*)&i1h[nxt][xcb][xf] = HH;
                *(ush4*)&x1l[nxt][xcb][xf] = HL;
                const int tn = (t + 2 < T_) ? t + 2 : T_ - 1;
                xc = *(const float4*)&x[xbase + (size_t)tn * F_];
            }
        }
        step_barrier();

        // ---------- P2 ----------
        if (wid < 4){
            if (t < T_){
                const float* p = &pre1[cb*PR1];
                const f32x4 gi = *(const f32x4*)&p[      u0];
                const f32x4 gf = *(const f32x4*)&p[ 64 + u0];
                const f32x4 gg = *(const f32x4*)&p[128 + u0];
                const f32x4 go = *(const f32x4*)&p[192 + u0];
                ush4 HH;
                #pragma unroll
                for (int q = 0; q < 4; ++q){
                    const float h = unit_combine(gi[q], gf[q], gg[q], go[q], c1[q]);
                    HH[q] = bf16_rne(h);
                }
                *(ush4*)&i1h[nxt][cb][32 + u0] = HH;   // h1(t) for L1-MFMA(t+1)
                *(ush4*)&i2h[cur][cb][u0]      = HH;   // h1(t) for L2-MFMA(t)
            }
        } else if (wid >= 8){
            const int k = t - 1;
            if (k >= 0 && k < T_){
                // i2h[nxt] = [h1(k) | h2(k-1)]
                const unsigned short* ph = &i2h[nxt][0][0] + bb*IMW + 8*kg;
                bf16x8 vh[3];
                #pragma unroll
                for (int kb = 0; kb < 3; ++kb)
                    vh[kb] = *(const bf16x8*)(ph + 32*kb);
                __builtin_amdgcn_s_setprio(1);
                f32x4 a0 = bfr[0], a1 = bfr[1];
                #pragma unroll
                for (int kb = 0; kb < 3; ++kb){
                    a0 = MFMA(wh[0][kb], vh[kb], a0);
                    a1 = MFMA(wh[1][kb], vh[kb], a1);
                }
                #pragma unroll
                for (int kb = 0; kb < 3; ++kb){
                    a0 = MFMA(wl[0][kb], vh[kb], a0);
                    a1 = MFMA(wl[1][kb], vh[kb], a1);
                }
                __builtin_amdgcn_s_setprio(0);
                *(f32x4*)&pre2[bb*PR2 + offs[0] + 4*kg] = a0;
                *(f32x4*)&pre2[bb*PR2 + offs[1] + 4*kg] = a1;
            }
        }
        step_barrier();
    }

    __syncthreads();
    // ===== head: fc1(16)+relu, fc2(1) =====
    if (tid < NBB * 16){
        const int b = tid >> 4, j2 = tid & 15;
        float a = b_fc1[j2];
        #pragma unroll
        for (int kk = 0; kk < 32; ++kk) a = fmaf(W_fc1[j2*32 + kk], hfin[b][kk], a);
        hd[b][j2] = fmaxf(a, 0.f);
    }
    __syncthreads();
    if (tid < NBB){
        float a = b_fc2[0];
        #pragma unroll
        for (int kk = 0; kk < 16; ++kk) a = fmaf(W_fc2[kk], hd[tid][kk], a);
        out[b0 + tid] = a;
    }
}

extern "C" void kernel_launch(void* const* d_in, const int* in_sizes, int n_in,
                              void* d_out, int out_size, void* d_ws, size_t ws_size,
                              hipStream_t stream) {
    const float* x     = (const float*)d_in[0];
    const float* W_ih1 = (const float*)d_in[1];
    const float* W_hh1 = (const float*)d_in[2];
    const float* b_ih1 = (const float*)d_in[3];
    const float* b_hh1 = (const float*)d_in[4];
    const float* W_ih2 = (const float*)d_in[5];
    const float* W_hh2 = (const float*)d_in[6];
    const float* b_ih2 = (const float*)d_in[7];
    const float* b_hh2 = (const float*)d_in[8];
    const float* W_fc1 = (const float*)d_in[9];
    const float* b_fc1 = (const float*)d_in[10];
    const float* W_fc2 = (const float*)d_in[11];
    const float* b_fc2 = (const float*)d_in[12];
    float* out = (float*)d_out;

    const int B = in_sizes[0] / (T_ * F_);   // 4096
    dim3 grid(B / NBB), block(TPB);          // 256 blocks, 1/CU, 12 waves
    hipLaunchKernelGGL(lstm_mfma, grid, block, 0, stream,
                       x, W_ih1, W_hh1, b_ih1, b_hh1,
                       W_ih2, W_hh2, b_ih2, b_hh2,
                       W_fc1, b_fc1, W_fc2, b_fc2, out);
}

// Round 22
// 248.037 us; speedup vs baseline: 1.6051x; 1.0135x over previous
//
#include <hip/hip_runtime.h>

#define T_   256
#define F_   32
#define NBB  16     // full 16-wide fragments
#define TPB  768    // 12 waves: 0-7 L1-role, 8-11 L2-role
#define IMW  136    // merged image row: [x(32)|h1(64)|h2(32)|pad(8)] ushorts
#define XLW  40     // x-lo row pitch (ushorts)
#define PR1  260    // pre1 row stride (f32)
#define PR2  132

typedef __attribute__((ext_vector_type(8))) short bf16x8;
typedef __attribute__((ext_vector_type(4))) float f32x4;
typedef __attribute__((ext_vector_type(4))) unsigned short ush4;

#define K1f  (-1.44269504f)   // -log2(e)   : sigmoid gates
#define K2f  (-2.88539008f)   // -2*log2(e) : tanh gate & tanh(c)

__device__ __forceinline__ unsigned short bf16_rne(float x){
    unsigned u = __float_as_uint(x);
    u += 0x7FFF + ((u >> 16) & 1);
    return (unsigned short)(u >> 16);
}
__device__ __forceinline__ void bf16_split(float x, unsigned short& h, unsigned short& l){
    h = bf16_rne(x);
    float xr = __uint_as_float(((unsigned)h) << 16);
    l = bf16_rne(x - xr);
}
__device__ __forceinline__ void make_frags_s(const float* __restrict__ p8, float s,
                                             bf16x8& fh, bf16x8& fl){
    #pragma unroll
    for (int e = 0; e < 8; ++e){
        unsigned short h, l; bf16_split(s * p8[e], h, l);
        fh[e] = (short)h; fl[e] = (short)l;
    }
}
__device__ __forceinline__ float sigm_pre(float p){   // p = -log2e*x
    return __builtin_amdgcn_rcpf(1.f + __builtin_amdgcn_exp2f(p));
}
__device__ __forceinline__ float tanh_pre(float p){   // p = -2log2e*x
    return fmaf(2.f, __builtin_amdgcn_rcpf(1.f + __builtin_amdgcn_exp2f(p)), -1.f);
}
__device__ __forceinline__ float unit_combine(float gi, float gf, float gg, float go, float& c){
    const float i_ = sigm_pre(gi);
    const float f_ = sigm_pre(gf);
    const float g_ = tanh_pre(gg);
    const float o_ = sigm_pre(go);
    c = fmaf(f_, c, i_ * g_);
    return o_ * tanh_pre(K2f * c);
}

#define MFMA(A,B,C) __builtin_amdgcn_mfma_f32_16x16x32_bf16((A),(B),(C),0,0,0)

// LDS-visibility barrier WITHOUT vmcnt drain (x-loads stay in flight).
__device__ __forceinline__ void step_barrier(){
    asm volatile("s_waitcnt lgkmcnt(0)" ::: "memory");
    __builtin_amdgcn_s_barrier();
}

// (768,3): r18's proven envelope (VGPR~64 + AGPR weights, no spill).
__global__ __launch_bounds__(TPB, 3) void lstm_mfma(
    const float* __restrict__ x,      // [4096,256,32]
    const float* __restrict__ W_ih1,  // [256,32]
    const float* __restrict__ W_hh1,  // [256,64]
    const float* __restrict__ b_ih1,  // [256]
    const float* __restrict__ b_hh1,  // [256]
    const float* __restrict__ W_ih2,  // [128,64]
    const float* __restrict__ W_hh2,  // [128,32]
    const float* __restrict__ b_ih2,  // [128]
    const float* __restrict__ b_hh2,  // [128]
    const float* __restrict__ W_fc1,  // [16,32]
    const float* __restrict__ b_fc1,  // [16]
    const float* __restrict__ W_fc2,  // [1,16]
    const float* __restrict__ b_fc2,  // [1]
    float* __restrict__ out)          // [4096]
{
    const int tid  = threadIdx.x;
    const int lane = tid & 63;
    const int wid  = tid >> 6;        // 0..11
    const int bb   = lane & 15;       // fragment col = batch
    const int kg   = (lane >> 4) & 3; // k-group of 8
    const int b0   = blockIdx.x * NBB;

    // merged image: [x(32) | h1(64) | h2(32) | pad] per batch, double-buffered
    __shared__ __align__(16) unsigned short i12[2][NBB][IMW];
    __shared__ __align__(16) unsigned short x1l[2][NBB][XLW];   // x lo sidecar
    __shared__ __align__(16) float pre1[NBB * PR1];
    __shared__ __align__(16) float pre2[NBB * PR2];
    __shared__ float hfin[NBB][32];
    __shared__ float hd[NBB][16];

    // ===== weight fragments: 2 tiles/wave (hi+lo, pre-scaled) — r18 =====
    bf16x8 wh[2][3], wl[2][3];
    f32x4  bfr[2];
    int    offs[2];
    if (wid < 8){
        #pragma unroll
        for (int tt = 0; tt < 2; ++tt){
            const int Tt = 2*wid + tt;
            const int g = Tt >> 2, rb = Tt & 3;
            const float s = (g == 2) ? K2f : K1f;
            offs[tt] = 64*g + 16*rb;
            const int r = offs[tt] + bb;
            make_frags_s(&W_ih1[r*32 +      8*kg], s, wh[tt][0], wl[tt][0]);
            make_frags_s(&W_hh1[r*64 +      8*kg], s, wh[tt][1], wl[tt][1]);
            make_frags_s(&W_hh1[r*64 + 32 + 8*kg], s, wh[tt][2], wl[tt][2]);
            #pragma unroll
            for (int q = 0; q < 4; ++q){
                const int row = offs[tt] + 4*kg + q;
                bfr[tt][q] = s * (b_ih1[row] + b_hh1[row]);
            }
        }
    } else {
        const int j = wid - 8;
        #pragma unroll
        for (int tt = 0; tt < 2; ++tt){
            const int St = 2*j + tt;
            const int g = St >> 1, rb = St & 1;
            const float s = (g == 2) ? K2f : K1f;
            offs[tt] = 32*g + 16*rb;
            const int r = offs[tt] + bb;
            make_frags_s(&W_ih2[r*64 +      8*kg], s, wh[tt][0], wl[tt][0]);
            make_frags_s(&W_ih2[r*64 + 32 + 8*kg], s, wh[tt][1], wl[tt][1]);
            make_frags_s(&W_hh2[r*32 +      8*kg], s, wh[tt][2], wl[tt][2]);
            #pragma unroll
            for (int q = 0; q < 4; ++q){
                const int row = offs[tt] + 4*kg + q;
                bfr[tt][q] = s * (b_ih2[row] + b_hh2[row]);
            }
        }
    }

    // ===== combine / x ownership (r21 f32x4 maps) =====
    // L1-combine (waves 0-3, P2): batch cb=tid>>4, units u0..u0+3
    const int cb = tid >> 4;            // valid for tid<256
    const int u0 = (tid & 15) * 4;
    float c1[4] = {0.f, 0.f, 0.f, 0.f};
    // L2-combine (waves 8-9, P1): c2t in 0..127: batch c2t>>3, units (c2t&7)*4
    const int c2t = tid & 127;
    const int cb2 = c2t >> 3;
    const int v0  = (c2t & 7) * 4;
    float c2[4] = {0.f, 0.f, 0.f, 0.f};
    // x-staging (waves 10-11, P1): xt in 0..127: batch xt>>3, floats (xt&7)*4
    const int xt  = tid & 127;
    const int xcb = xt >> 3;
    const int xf  = (xt & 7) * 4;
    const size_t xbase = (size_t)(b0 + xcb) * (T_*F_) + xf;
    float4 xc = make_float4(0.f, 0.f, 0.f, 0.f);

    // ===== init: zero merged image (h regions must start 0), stage x(0) =====
    for (int i = tid; i < 2*NBB*IMW; i += TPB) (&i12[0][0][0])[i] = 0;
    __syncthreads();
    if (wid >= 10){
        float4 x0 = *(const float4*)&x[xbase];
        ush4 HH, HL;
        unsigned short h, l;
        bf16_split(x0.x, h, l); HH[0]=h; HL[0]=l;
        bf16_split(x0.y, h, l); HH[1]=h; HL[1]=l;
        bf16_split(x0.z, h, l); HH[2]=h; HL[2]=l;
        bf16_split(x0.w, h, l); HH[3]=h; HL[3]=l;
        *(ush4*)&i12[0][xcb][xf] = HH;
        *(ush4*)&x1l[0][xcb][xf] = HL;
        xc = *(const float4*)&x[xbase + F_];
    }
    __syncthreads();

    // ===== main loop (r18 schedule, merged image) =====
    // P1(t): L1-MFMA(t) reads i12[cur][0..95] -> pre1 [w0-7]
    //        L2-comb(t-2) -> h2 -> i12[cur][96..127] [w8-9]   (disjoint cols)
    //        x(t+1) -> i12[nxt][0..31] + x1l[nxt] [w10-11]
    // P2(t): L1-comb(t) -> h1 -> i12[nxt][32..95] [w0-3]      (single write!)
    //        L2-MFMA(t-1) reads i12[cur][32..127] -> pre2 [w8-11]
    for (int t = 0; t <= T_ + 1; ++t){
        const int cur = t & 1, nxt = cur ^ 1;

        // ---------- P1 ----------
        if (wid < 8){
            if (t < T_){
                const unsigned short* ph = &i12[cur][0][0] + bb*IMW + 8*kg;
                bf16x8 vh[3];
                #pragma unroll
                for (int kb = 0; kb < 3; ++kb)
                    vh[kb] = *(const bf16x8*)(ph + 32*kb);
                const bf16x8 vl0 = *(const bf16x8*)&x1l[cur][bb][8*kg];
                __builtin_amdgcn_s_setprio(1);
                f32x4 a0 = bfr[0], a1 = bfr[1];
                #pragma unroll
                for (int kb = 0; kb < 3; ++kb){
                    a0 = MFMA(wh[0][kb], vh[kb], a0);
                    a1 = MFMA(wh[1][kb], vh[kb], a1);
                }
                #pragma unroll
                for (int kb = 0; kb < 3; ++kb){
                    a0 = MFMA(wl[0][kb], vh[kb], a0);
                    a1 = MFMA(wl[1][kb], vh[kb], a1);
                }
                a0 = MFMA(wh[0][0], vl0, a0);   // x-lo (k 0..31 only)
                a1 = MFMA(wh[1][0], vl0, a1);
                __builtin_amdgcn_s_setprio(0);
                *(f32x4*)&pre1[bb*PR1 + offs[0] + 4*kg] = a0;
                *(f32x4*)&pre1[bb*PR1 + offs[1] + 4*kg] = a1;
            }
        } else if (wid < 10){
            const int m = t - 2;
            if (m >= 0 && m < T_){
                const float* p = &pre2[cb2*PR2];
                const f32x4 gi = *(const f32x4*)&p[     v0];
                const f32x4 gf = *(const f32x4*)&p[32 + v0];
                const f32x4 gg = *(const f32x4*)&p[64 + v0];
                const f32x4 go = *(const f32x4*)&p[96 + v0];
                ush4 HH;
                float hv[4];
                #pragma unroll
                for (int q = 0; q < 4; ++q){
                    hv[q] = unit_combine(gi[q], gf[q], gg[q], go[q], c2[q]);
                    HH[q] = bf16_rne(hv[q]);
                }
                // h2(m) -> i12[cur][96+v0]; read by L2-MFMA(t-1) in P2(t)
                *(ush4*)&i12[cur][cb2][96 + v0] = HH;
                if (m == T_ - 1){
                    hfin[cb2][v0]   = hv[0]; hfin[cb2][v0+1] = hv[1];
                    hfin[cb2][v0+2] = hv[2]; hfin[cb2][v0+3] = hv[3];
                }
            }
        } else {
            if (t + 1 < T_){
                ush4 HH, HL;
                unsigned short h, l;
                bf16_split(xc.x, h, l); HH[0]=h; HL[0]=l;
                bf16_split(xc.y, h, l); HH[1]=h; HL[1]=l;
                bf16_split(xc.z, h, l); HH[2]=h; HL[2]=l;
                bf16_split(xc.w, h, l); HH[3]=h; HL[3]=l;
                *(ush4*)&i12[nxt][xcb][xf] = HH;
                *(ush4*)&x1l[nxt][xcb][xf] = HL;
                const int tn = (t + 2 < T_) ? t + 2 : T_ - 1;
                xc = *(const float4*)&x[xbase + (size_t)tn * F_];
            }
        }
        step_barrier();

        // ---------- P2 ----------
        if (wid < 4){
            if (t < T_){
                const float* p = &pre1[cb*PR1];
                const f32x4 gi = *(const f32x4*)&p[      u0];
                const f32x4 gf = *(const f32x4*)&p[ 64 + u0];
                const f32x4 gg = *(const f32x4*)&p[128 + u0];
                const f32x4 go = *(const f32x4*)&p[192 + u0];
                ush4 HH;
                #pragma unroll
                for (int q = 0; q < 4; ++q){
                    const float h = unit_combine(gi[q], gf[q], gg[q], go[q], c1[q]);
                    HH[q] = bf16_rne(h);
                }
                // SINGLE h1(t) write: read by L1-MFMA(t+1) (cols 32..95 of i12[nxt])
                // and by L2-MFMA(t) in P2(t+1) (same buffer, cols 32..95)
                *(ush4*)&i12[nxt][cb][32 + u0] = HH;
            }
        } else if (wid >= 8){
            const int k = t - 1;
            if (k >= 0 && k < T_){
                // i12[cur][32..127] = [h1(k) | h2(k-1)]
                const unsigned short* ph = &i12[cur][0][0] + bb*IMW + 32 + 8*kg;
                bf16x8 vh[3];
                #pragma unroll
                for (int kb = 0; kb < 3; ++kb)
                    vh[kb] = *(const bf16x8*)(ph + 32*kb);
                __builtin_amdgcn_s_setprio(1);
                f32x4 a0 = bfr[0], a1 = bfr[1];
                #pragma unroll
                for (int kb = 0; kb < 3; ++kb){
                    a0 = MFMA(wh[0][kb], vh[kb], a0);
                    a1 = MFMA(wh[1][kb], vh[kb], a1);
                }
                #pragma unroll
                for (int kb = 0; kb < 3; ++kb){
                    a0 = MFMA(wl[0][kb], vh[kb], a0);
                    a1 = MFMA(wl[1][kb], vh[kb], a1);
                }
                __builtin_amdgcn_s_setprio(0);
                *(f32x4*)&pre2[bb*PR2 + offs[0] + 4*kg] = a0;
                *(f32x4*)&pre2[bb*PR2 + offs[1] + 4*kg] = a1;
            }
        }
        step_barrier();
    }

    __syncthreads();
    // ===== head: fc1(16)+relu, fc2(1) =====
    if (tid < NBB * 16){
        const int b = tid >> 4, j2 = tid & 15;
        float a = b_fc1[j2];
        #pragma unroll
        for (int kk = 0; kk < 32; ++kk) a = fmaf(W_fc1[j2*32 + kk], hfin[b][kk], a);
        hd[b][j2] = fmaxf(a, 0.f);
    }
    __syncthreads();
    if (tid < NBB){
        float a = b_fc2[0];
        #pragma unroll
        for (int kk = 0; kk < 16; ++kk) a = fmaf(W_fc2[kk], hd[tid][kk], a);
        out[b0 + tid] = a;
    }
}

extern "C" void kernel_launch(void* const* d_in, const int* in_sizes, int n_in,
                              void* d_out, int out_size, void* d_ws, size_t ws_size,
                              hipStream_t stream) {
    const float* x     = (const float*)d_in[0];
    const float* W_ih1 = (const float*)d_in[1];
    const float* W_hh1 = (const float*)d_in[2];
    const float* b_ih1 = (const float*)d_in[3];
    const float* b_hh1 = (const float*)d_in[4];
    const float* W_ih2 = (const float*)d_in[5];
    const float* W_hh2 = (const float*)d_in[6];
    const float* b_ih2 = (const float*)d_in[7];
    const float* b_hh2 = (const float*)d_in[8];
    const float* W_fc1 = (const float*)d_in[9];
    const float* b_fc1 = (const float*)d_in[10];
    const float* W_fc2 = (const float*)d_in[11];
    const float* b_fc2 = (const float*)d_in[12];
    float* out = (float*)d_out;

    const int B = in_sizes[0] / (T_ * F_);   // 4096
    dim3 grid(B / NBB), block(TPB);          // 256 blocks, 1/CU, 12 waves
    hipLaunchKernelGGL(lstm_mfma, grid, block, 0, stream,
                       x, W_ih1, W_hh1, b_ih1, b_hh1,
                       W_ih2, W_hh2, b_ih2, b_hh2,
                       W_fc1, b_fc1, W_fc2, b_fc2, out);
}

// Round 23
// 236.873 us; speedup vs baseline: 1.6807x; 1.0471x over previous
//
#include <hip/hip_runtime.h>

#define T_   256
#define F_   32
#define NBB  16     // full 16-wide fragments
#define TPB  512    // 8 waves: 0-3 L1 (gate-colocated), 4-5 L2 (gate-colocated), 6-7 x
#define IMW  136    // merged image row: [x(32)|h1(64)|h2(32)|pad(8)] ushorts (272B: odd*16)
#define XLW  40     // x-lo row pitch (ushorts)

typedef __attribute__((ext_vector_type(8))) short bf16x8;
typedef __attribute__((ext_vector_type(4))) float f32x4;
typedef __attribute__((ext_vector_type(4))) unsigned short ush4;

#define K1f  (-1.44269504f)   // -log2(e)   : sigmoid gates
#define K2f  (-2.88539008f)   // -2*log2(e) : tanh gate & tanh(c)

__device__ __forceinline__ unsigned short bf16_rne(float x){
    unsigned u = __float_as_uint(x);
    u += 0x7FFF + ((u >> 16) & 1);
    return (unsigned short)(u >> 16);
}
__device__ __forceinline__ void bf16_split(float x, unsigned short& h, unsigned short& l){
    h = bf16_rne(x);
    float xr = __uint_as_float(((unsigned)h) << 16);
    l = bf16_rne(x - xr);
}
__device__ __forceinline__ void make_frags_s(const float* __restrict__ p8, float s,
                                             bf16x8& fh, bf16x8& fl){
    #pragma unroll
    for (int e = 0; e < 8; ++e){
        unsigned short h, l; bf16_split(s * p8[e], h, l);
        fh[e] = (short)h; fl[e] = (short)l;
    }
}
__device__ __forceinline__ float sigm_pre(float p){   // p = -log2e*x
    return __builtin_amdgcn_rcpf(1.f + __builtin_amdgcn_exp2f(p));
}
__device__ __forceinline__ float tanh_pre(float p){   // p = -2log2e*x
    return fmaf(2.f, __builtin_amdgcn_rcpf(1.f + __builtin_amdgcn_exp2f(p)), -1.f);
}
__device__ __forceinline__ float unit_combine(float gi, float gf, float gg, float go, float& c){
    const float i_ = sigm_pre(gi);
    const float f_ = sigm_pre(gf);
    const float g_ = tanh_pre(gg);
    const float o_ = sigm_pre(go);
    c = fmaf(f_, c, i_ * g_);
    return o_ * tanh_pre(K2f * c);
}

#define MFMA(A,B,C) __builtin_amdgcn_mfma_f32_16x16x32_bf16((A),(B),(C),0,0,0)

// LDS-visibility barrier WITHOUT vmcnt drain: x-waves' global loads stay in
// flight across it. (r6's one-barrier failed precisely because __syncthreads
// drained vmcnt ~900cy every step; this is the fix that resurrects it.)
__device__ __forceinline__ void step_barrier(){
    asm volatile("s_waitcnt lgkmcnt(0)" ::: "memory");
    __builtin_amdgcn_s_barrier();
}

// (512,2): 256-reg envelope for 4-gate-colocated waves (24 bf16x8 weights).
// r19 proved these spill at (768,3); r6 proved they fit at (512,2).
__global__ __launch_bounds__(TPB, 2) void lstm_mfma(
    const float* __restrict__ x,      // [4096,256,32]
    const float* __restrict__ W_ih1,  // [256,32]
    const float* __restrict__ W_hh1,  // [256,64]
    const float* __restrict__ b_ih1,  // [256]
    const float* __restrict__ b_hh1,  // [256]
    const float* __restrict__ W_ih2,  // [128,64]
    const float* __restrict__ W_hh2,  // [128,32]
    const float* __restrict__ b_ih2,  // [128]
    const float* __restrict__ b_hh2,  // [128]
    const float* __restrict__ W_fc1,  // [16,32]
    const float* __restrict__ b_fc1,  // [16]
    const float* __restrict__ W_fc2,  // [1,16]
    const float* __restrict__ b_fc2,  // [1]
    float* __restrict__ out)          // [4096]
{
    const int tid  = threadIdx.x;
    const int lane = tid & 63;
    const int wid  = tid >> 6;        // 0..7
    const int bb   = lane & 15;       // fragment col = batch
    const int kg   = (lane >> 4) & 3; // k-group of 8
    const int b0   = blockIdx.x * NBB;

    // merged image [x(32)|h1(64)|h2(32)|pad], double-buffered; x-lo sidecar
    __shared__ __align__(16) unsigned short i12[2][NBB][IMW];
    __shared__ __align__(16) unsigned short x1l[2][NBB][XLW];
    __shared__ float hfin[NBB][32];
    __shared__ float hd[NBB][16];

    // ===== weight fragments: GATE-COLOCATED, 4 gate-tiles per MFMA wave =====
    // L1 waves 0-3: wave w owns units 16w..16w+15, all 4 gates (rows 64g+16w)
    // L2 waves 4-5: wave j owns units 16j..16j+15, all 4 gates (rows 32g+16j)
    bf16x8 wh[4][3], wl[4][3];
    f32x4  bfr[4];
    if (wid < 4){
        #pragma unroll
        for (int g = 0; g < 4; ++g){
            const float s = (g == 2) ? K2f : K1f;
            const int r = 64*g + 16*wid + bb;
            make_frags_s(&W_ih1[r*32 +      8*kg], s, wh[g][0], wl[g][0]);
            make_frags_s(&W_hh1[r*64 +      8*kg], s, wh[g][1], wl[g][1]);
            make_frags_s(&W_hh1[r*64 + 32 + 8*kg], s, wh[g][2], wl[g][2]);
            #pragma unroll
            for (int q = 0; q < 4; ++q){
                const int row = 64*g + 16*wid + 4*kg + q;
                bfr[g][q] = s * (b_ih1[row] + b_hh1[row]);
            }
        }
    } else if (wid < 6){
        const int j = wid - 4;
        #pragma unroll
        for (int g = 0; g < 4; ++g){
            const float s = (g == 2) ? K2f : K1f;
            const int r = 32*g + 16*j + bb;
            make_frags_s(&W_ih2[r*64 +      8*kg], s, wh[g][0], wl[g][0]);
            make_frags_s(&W_ih2[r*64 + 32 + 8*kg], s, wh[g][1], wl[g][1]);
            make_frags_s(&W_hh2[r*32 +      8*kg], s, wh[g][2], wl[g][2]);
            #pragma unroll
            for (int q = 0; q < 4; ++q){
                const int row = 32*g + 16*j + 4*kg + q;
                bfr[g][q] = s * (b_ih2[row] + b_hh2[row]);
            }
        }
    }

    float cc[4] = {0.f, 0.f, 0.f, 0.f};   // c1 (L1 waves) / c2 (L2 waves), units 4kg+q

    // x-staging (waves 6-7): 128 threads × float4 = 16 batches × 32 floats
    const int xt  = tid & 127;
    const int xcb = xt >> 3;
    const int xf  = (xt & 7) * 4;
    const size_t xbase = (size_t)(b0 + xcb) * (T_*F_) + xf;
    float4 xc = make_float4(0.f, 0.f, 0.f, 0.f);

    // ===== init: zero image (h regions must start 0), stage x(0), preload x(1) =====
    for (int i = tid; i < 2*NBB*IMW; i += TPB) (&i12[0][0][0])[i] = 0;
    __syncthreads();
    if (wid >= 6){
        float4 x0 = *(const float4*)&x[xbase];
        ush4 HH, HL;
        unsigned short h, l;
        bf16_split(x0.x, h, l); HH[0]=h; HL[0]=l;
        bf16_split(x0.y, h, l); HH[1]=h; HL[1]=l;
        bf16_split(x0.z, h, l); HH[2]=h; HL[2]=l;
        bf16_split(x0.w, h, l); HH[3]=h; HL[3]=l;
        *(ush4*)&i12[0][xcb][xf] = HH;
        *(ush4*)&x1l[0][xcb][xf] = HL;
        xc = *(const float4*)&x[xbase + F_];
    }
    __syncthreads();

    // ===== main loop: ONE lgkm-only barrier per step =====
    // iter t: L1(t): read i12[cur][0..95]+x1l[cur] -> MFMA -> in-reg combine
    //               -> h1(t) -> i12[nxt][32..95]                       [w0-3]
    //         L2(t-1): read i12[cur][32..127] -> MFMA -> in-reg combine
    //               -> h2(t-1) -> i12[nxt][96..127]                    [w4-5]
    //         x(t+1) -> i12[nxt][0..31] + x1l[nxt]; issue load x(t+2)  [w6-7]
    for (int t = 0; t <= T_; ++t){
        const int cur = t & 1, nxt = cur ^ 1;

        if (wid < 4){
            if (t < T_){
                const unsigned short* ph = &i12[cur][0][0] + bb*IMW + 8*kg;
                bf16x8 vh[3];
                #pragma unroll
                for (int kb = 0; kb < 3; ++kb)
                    vh[kb] = *(const bf16x8*)(ph + 32*kb);
                const bf16x8 vl0 = *(const bf16x8*)&x1l[cur][bb][8*kg];
                __builtin_amdgcn_s_setprio(1);
                f32x4 a0 = bfr[0], a1 = bfr[1], a2 = bfr[2], a3 = bfr[3];
                #pragma unroll
                for (int kb = 0; kb < 3; ++kb){
                    a0 = MFMA(wh[0][kb], vh[kb], a0);
                    a1 = MFMA(wh[1][kb], vh[kb], a1);
                    a2 = MFMA(wh[2][kb], vh[kb], a2);
                    a3 = MFMA(wh[3][kb], vh[kb], a3);
                }
                #pragma unroll
                for (int kb = 0; kb < 3; ++kb){
                    a0 = MFMA(wl[0][kb], vh[kb], a0);
                    a1 = MFMA(wl[1][kb], vh[kb], a1);
                    a2 = MFMA(wl[2][kb], vh[kb], a2);
                    a3 = MFMA(wl[3][kb], vh[kb], a3);
                }
                a0 = MFMA(wh[0][0], vl0, a0);   // x-lo (k 0..31 only)
                a1 = MFMA(wh[1][0], vl0, a1);
                a2 = MFMA(wh[2][0], vl0, a2);
                a3 = MFMA(wh[3][0], vl0, a3);
                __builtin_amdgcn_s_setprio(0);
                // in-register combine: lane owns units 16*wid+4*kg+q of batch bb
                ush4 HH;
                #pragma unroll
                for (int q = 0; q < 4; ++q){
                    const float h = unit_combine(a0[q], a1[q], a2[q], a3[q], cc[q]);
                    HH[q] = bf16_rne(h);
                }
                *(ush4*)&i12[nxt][bb][32 + 16*wid + 4*kg] = HH;
            }
        } else if (wid < 6){
            if (t >= 1){   // compute L2(t-1)
                const unsigned short* ph = &i12[cur][0][0] + bb*IMW + 32 + 8*kg;
                bf16x8 vh[3];
                #pragma unroll
                for (int kb = 0; kb < 3; ++kb)
                    vh[kb] = *(const bf16x8*)(ph + 32*kb);
                __builtin_amdgcn_s_setprio(1);
                f32x4 a0 = bfr[0], a1 = bfr[1], a2 = bfr[2], a3 = bfr[3];
                #pragma unroll
                for (int kb = 0; kb < 3; ++kb){
                    a0 = MFMA(wh[0][kb], vh[kb], a0);
                    a1 = MFMA(wh[1][kb], vh[kb], a1);
                    a2 = MFMA(wh[2][kb], vh[kb], a2);
                    a3 = MFMA(wh[3][kb], vh[kb], a3);
                }
                #pragma unroll
                for (int kb = 0; kb < 3; ++kb){
                    a0 = MFMA(wl[0][kb], vh[kb], a0);
                    a1 = MFMA(wl[1][kb], vh[kb], a1);
                    a2 = MFMA(wl[2][kb], vh[kb], a2);
                    a3 = MFMA(wl[3][kb], vh[kb], a3);
                }
                __builtin_amdgcn_s_setprio(0);
                const int j = wid - 4;
                ush4 HH;
                float hv[4];
                #pragma unroll
                for (int q = 0; q < 4; ++q){
                    hv[q] = unit_combine(a0[q], a1[q], a2[q], a3[q], cc[q]);
                    HH[q] = bf16_rne(hv[q]);
                }
                *(ush4*)&i12[nxt][bb][96 + 16*j + 4*kg] = HH;
                if (t - 1 == T_ - 1){
                    const int u = 16*j + 4*kg;
                    hfin[bb][u]   = hv[0]; hfin[bb][u+1] = hv[1];
                    hfin[bb][u+2] = hv[2]; hfin[bb][u+3] = hv[3];
                }
            }
        } else {
            if (t + 1 < T_){
                ush4 HH, HL;
                unsigned short h, l;
                bf16_split(xc.x, h, l); HH[0]=h; HL[0]=l;
                bf16_split(xc.y, h, l); HH[1]=h; HL[1]=l;
                bf16_split(xc.z, h, l); HH[2]=h; HL[2]=l;
                bf16_split(xc.w, h, l); HH[3]=h; HL[3]=l;
                *(ush4*)&i12[nxt][xcb][xf] = HH;
                *(ush4*)&x1l[nxt][xcb][xf] = HL;
                const int tn = (t + 2 < T_) ? t + 2 : T_ - 1;
                xc = *(const float4*)&x[xbase + (size_t)tn * F_];
            }
        }
        step_barrier();
    }

    __syncthreads();
    // ===== head: fc1(16)+relu, fc2(1) =====
    if (tid < NBB * 16){
        const int b = tid >> 4, j2 = tid & 15;
        float a = b_fc1[j2];
        #pragma unroll
        for (int kk = 0; kk < 32; ++kk) a = fmaf(W_fc1[j2*32 + kk], hfin[b][kk], a);
        hd[b][j2] = fmaxf(a, 0.f);
    }
    __syncthreads();
    if (tid < NBB){
        float a = b_fc2[0];
        #pragma unroll
        for (int kk = 0; kk < 16; ++kk) a = fmaf(W_fc2[kk], hd[tid][kk], a);
        out[b0 + tid] = a;
    }
}

extern "C" void kernel_launch(void* const* d_in, const int* in_sizes, int n_in,
                              void* d_out, int out_size, void* d_ws, size_t ws_size,
                              hipStream_t stream) {
    const float* x     = (const float*)d_in[0];
    const float* W_ih1 = (const float*)d_in[1];
    const float* W_hh1 = (const float*)d_in[2];
    const float* b_ih1 = (const float*)d_in[3];
    const float* b_hh1 = (const float*)d_in[4];
    const float* W_ih2 = (const float*)d_in[5];
    const float* W_hh2 = (const float*)d_in[6];
    const float* b_ih2 = (const float*)d_in[7];
    const float* b_hh2 = (const float*)d_in[8];
    const float* W_fc1 = (const float*)d_in[9];
    const float* b_fc1 = (const float*)d_in[10];
    const float* W_fc2 = (const float*)d_in[11];
    const float* b_fc2 = (const float*)d_in[12];
    float* out = (float*)d_out;

    const int B = in_sizes[0] / (T_ * F_);   // 4096
    dim3 grid(B / NBB), block(TPB);          // 256 blocks, 1/CU, 8 waves
    hipLaunchKernelGGL(lstm_mfma, grid, block, 0, stream,
                       x, W_ih1, W_hh1, b_ih1, b_hh1,
                       W_ih2, W_hh2, b_ih2, b_hh2,
                       W_fc1, b_fc1, W_fc2, b_fc2, out);
}

// Round 24
// 228.719 us; speedup vs baseline: 1.7407x; 1.0357x over previous
//
#include <hip/hip_runtime.h>

#define T_   256
#define F_   32
#define NBB  16     // full 16-wide fragments
#define TPB  512    // 8 waves: 0-3 L1 (gate-colocated), 4-5 L2 (gate-colocated), 6-7 x
#define IMW  136    // merged image row: [x(32)|h1(64)|h2(32)|pad(8)] ushorts

typedef __attribute__((ext_vector_type(8))) short bf16x8;
typedef __attribute__((ext_vector_type(4))) float f32x4;
typedef __attribute__((ext_vector_type(4))) unsigned short ush4;

#define K1f  (-1.44269504f)   // -log2(e)   : sigmoid gates
#define K2f  (-2.88539008f)   // -2*log2(e) : tanh gate & tanh(c)

__device__ __forceinline__ unsigned short bf16_rne(float x){
    unsigned u = __float_as_uint(x);
    u += 0x7FFF + ((u >> 16) & 1);
    return (unsigned short)(u >> 16);
}
__device__ __forceinline__ void bf16_split(float x, unsigned short& h, unsigned short& l){
    h = bf16_rne(x);
    float xr = __uint_as_float(((unsigned)h) << 16);
    l = bf16_rne(x - xr);
}
__device__ __forceinline__ void make_frags_s(const float* __restrict__ p8, float s,
                                             bf16x8& fh, bf16x8& fl){
    #pragma unroll
    for (int e = 0; e < 8; ++e){
        unsigned short h, l; bf16_split(s * p8[e], h, l);
        fh[e] = (short)h; fl[e] = (short)l;
    }
}
__device__ __forceinline__ float sigm_pre(float p){   // p = -log2e*x
    return __builtin_amdgcn_rcpf(1.f + __builtin_amdgcn_exp2f(p));
}
__device__ __forceinline__ float tanh_pre(float p){   // p = -2log2e*x
    return fmaf(2.f, __builtin_amdgcn_rcpf(1.f + __builtin_amdgcn_exp2f(p)), -1.f);
}
__device__ __forceinline__ float unit_combine(float gi, float gf, float gg, float go, float& c){
    const float i_ = sigm_pre(gi);
    const float f_ = sigm_pre(gf);
    const float g_ = tanh_pre(gg);
    const float o_ = sigm_pre(go);
    c = fmaf(f_, c, i_ * g_);
    return o_ * tanh_pre(K2f * c);
}

#define MFMA(A,B,C) __builtin_amdgcn_mfma_f32_16x16x32_bf16((A),(B),(C),0,0,0)

// LDS-visibility barrier WITHOUT vmcnt drain (x-waves' loads stay in flight).
__device__ __forceinline__ void step_barrier(){
    asm volatile("s_waitcnt lgkmcnt(0)" ::: "memory");
    __builtin_amdgcn_s_barrier();
}

// (512,2): 256-reg envelope for 4-gate-colocated waves (24 bf16x8 weights).
__global__ __launch_bounds__(TPB, 2) void lstm_mfma(
    const float* __restrict__ x,      // [4096,256,32]
    const float* __restrict__ W_ih1,  // [256,32]
    const float* __restrict__ W_hh1,  // [256,64]
    const float* __restrict__ b_ih1,  // [256]
    const float* __restrict__ b_hh1,  // [256]
    const float* __restrict__ W_ih2,  // [128,64]
    const float* __restrict__ W_hh2,  // [128,32]
    const float* __restrict__ b_ih2,  // [128]
    const float* __restrict__ b_hh2,  // [128]
    const float* __restrict__ W_fc1,  // [16,32]
    const float* __restrict__ b_fc1,  // [16]
    const float* __restrict__ W_fc2,  // [1,16]
    const float* __restrict__ b_fc2,  // [1]
    float* __restrict__ out)          // [4096]
{
    const int tid  = threadIdx.x;
    const int lane = tid & 63;
    const int wid  = tid >> 6;        // 0..7
    const int bb   = lane & 15;       // fragment col = batch
    const int kg   = (lane >> 4) & 3; // k-group of 8
    const int b0   = blockIdx.x * NBB;

    // merged image [x(32)|h1(64)|h2(32)|pad], double-buffered (x now plain bf16)
    __shared__ __align__(16) unsigned short i12[2][NBB][IMW];
    __shared__ float hfin[NBB][32];
    __shared__ float hd[NBB][16];

    // ===== weight fragments: GATE-COLOCATED, 4 gate-tiles per MFMA wave =====
    bf16x8 wh[4][3], wl[4][3];
    f32x4  bfr[4];
    if (wid < 4){
        #pragma unroll
        for (int g = 0; g < 4; ++g){
            const float s = (g == 2) ? K2f : K1f;
            const int r = 64*g + 16*wid + bb;
            make_frags_s(&W_ih1[r*32 +      8*kg], s, wh[g][0], wl[g][0]);
            make_frags_s(&W_hh1[r*64 +      8*kg], s, wh[g][1], wl[g][1]);
            make_frags_s(&W_hh1[r*64 + 32 + 8*kg], s, wh[g][2], wl[g][2]);
            #pragma unroll
            for (int q = 0; q < 4; ++q){
                const int row = 64*g + 16*wid + 4*kg + q;
                bfr[g][q] = s * (b_ih1[row] + b_hh1[row]);
            }
        }
    } else if (wid < 6){
        const int j = wid - 4;
        #pragma unroll
        for (int g = 0; g < 4; ++g){
            const float s = (g == 2) ? K2f : K1f;
            const int r = 32*g + 16*j + bb;
            make_frags_s(&W_ih2[r*64 +      8*kg], s, wh[g][0], wl[g][0]);
            make_frags_s(&W_ih2[r*64 + 32 + 8*kg], s, wh[g][1], wl[g][1]);
            make_frags_s(&W_hh2[r*32 +      8*kg], s, wh[g][2], wl[g][2]);
            #pragma unroll
            for (int q = 0; q < 4; ++q){
                const int row = 32*g + 16*j + 4*kg + q;
                bfr[g][q] = s * (b_ih2[row] + b_hh2[row]);
            }
        }
    }

    float cc[4] = {0.f, 0.f, 0.f, 0.f};   // c1 (L1 waves) / c2 (L2 waves)

    // x-staging (waves 6-7): 128 threads × float4 = 16 batches × 32 floats
    const int xt  = tid & 127;
    const int xcb = xt >> 3;
    const int xf  = (xt & 7) * 4;
    const size_t xbase = (size_t)(b0 + xcb) * (T_*F_) + xf;
    float4 xc = make_float4(0.f, 0.f, 0.f, 0.f);

    // ===== init: zero image (h regions must start 0), stage x(0), preload x(1) =====
    for (int i = tid; i < 2*NBB*IMW; i += TPB) (&i12[0][0][0])[i] = 0;
    __syncthreads();
    if (wid >= 6){
        float4 x0 = *(const float4*)&x[xbase];
        ush4 HH;
        HH[0] = bf16_rne(x0.x); HH[1] = bf16_rne(x0.y);
        HH[2] = bf16_rne(x0.z); HH[3] = bf16_rne(x0.w);
        *(ush4*)&i12[0][xcb][xf] = HH;
        xc = *(const float4*)&x[xbase + F_];
    }
    __syncthreads();

    // ===== main loop: ONE lgkm-only barrier per step =====
    // iter t: L1(t): read i12[cur][0..95] -> 24 MFMA -> in-reg combine
    //               -> h1(t) -> i12[nxt][32..95]                       [w0-3]
    //         L2(t-1): read i12[cur][32..127] -> 24 MFMA -> in-reg combine
    //               -> h2(t-1) -> i12[nxt][96..127]                    [w4-5]
    //         x(t+1) -> i12[nxt][0..31]; issue load x(t+2)             [w6-7]
    for (int t = 0; t <= T_; ++t){
        const int cur = t & 1, nxt = cur ^ 1;

        if (wid < 4){
            if (t < T_){
                const unsigned short* ph = &i12[cur][0][0] + bb*IMW + 8*kg;
                bf16x8 vh[3];
                #pragma unroll
                for (int kb = 0; kb < 3; ++kb)
                    vh[kb] = *(const bf16x8*)(ph + 32*kb);
                f32x4 a0 = bfr[0], a1 = bfr[1], a2 = bfr[2], a3 = bfr[3];
                #pragma unroll
                for (int kb = 0; kb < 3; ++kb){
                    a0 = MFMA(wh[0][kb], vh[kb], a0);
                    a1 = MFMA(wh[1][kb], vh[kb], a1);
                    a2 = MFMA(wh[2][kb], vh[kb], a2);
                    a3 = MFMA(wh[3][kb], vh[kb], a3);
                }
                #pragma unroll
                for (int kb = 0; kb < 3; ++kb){
                    a0 = MFMA(wl[0][kb], vh[kb], a0);
                    a1 = MFMA(wl[1][kb], vh[kb], a1);
                    a2 = MFMA(wl[2][kb], vh[kb], a2);
                    a3 = MFMA(wl[3][kb], vh[kb], a3);
                }
                // in-register combine: lane owns units 16*wid+4*kg+q of batch bb
                ush4 HH;
                #pragma unroll
                for (int q = 0; q < 4; ++q){
                    const float h = unit_combine(a0[q], a1[q], a2[q], a3[q], cc[q]);
                    HH[q] = bf16_rne(h);
                }
                *(ush4*)&i12[nxt][bb][32 + 16*wid + 4*kg] = HH;
            }
        } else if (wid < 6){
            if (t >= 1){   // compute L2(t-1)
                const unsigned short* ph = &i12[cur][0][0] + bb*IMW + 32 + 8*kg;
                bf16x8 vh[3];
                #pragma unroll
                for (int kb = 0; kb < 3; ++kb)
                    vh[kb] = *(const bf16x8*)(ph + 32*kb);
                f32x4 a0 = bfr[0], a1 = bfr[1], a2 = bfr[2], a3 = bfr[3];
                #pragma unroll
                for (int kb = 0; kb < 3; ++kb){
                    a0 = MFMA(wh[0][kb], vh[kb], a0);
                    a1 = MFMA(wh[1][kb], vh[kb], a1);
                    a2 = MFMA(wh[2][kb], vh[kb], a2);
                    a3 = MFMA(wh[3][kb], vh[kb], a3);
                }
                #pragma unroll
                for (int kb = 0; kb < 3; ++kb){
                    a0 = MFMA(wl[0][kb], vh[kb], a0);
                    a1 = MFMA(wl[1][kb], vh[kb], a1);
                    a2 = MFMA(wl[2][kb], vh[kb], a2);
                    a3 = MFMA(wl[3][kb], vh[kb], a3);
                }
                const int j = wid - 4;
                ush4 HH;
                float hv[4];
                #pragma unroll
                for (int q = 0; q < 4; ++q){
                    hv[q] = unit_combine(a0[q], a1[q], a2[q], a3[q], cc[q]);
                    HH[q] = bf16_rne(hv[q]);
                }
                *(ush4*)&i12[nxt][bb][96 + 16*j + 4*kg] = HH;
                if (t - 1 == T_ - 1){
                    const int u = 16*j + 4*kg;
                    hfin[bb][u]   = hv[0]; hfin[bb][u+1] = hv[1];
                    hfin[bb][u+2] = hv[2]; hfin[bb][u+3] = hv[3];
                }
            }
        } else {
            if (t + 1 < T_){
                ush4 HH;
                HH[0] = bf16_rne(xc.x); HH[1] = bf16_rne(xc.y);
                HH[2] = bf16_rne(xc.z); HH[3] = bf16_rne(xc.w);
                *(ush4*)&i12[nxt][xcb][xf] = HH;
                const int tn = (t + 2 < T_) ? t + 2 : T_ - 1;
                xc = *(const float4*)&x[xbase + (size_t)tn * F_];
            }
        }
        step_barrier();
    }

    __syncthreads();
    // ===== head: fc1(16)+relu, fc2(1) =====
    if (tid < NBB * 16){
        const int b = tid >> 4, j2 = tid & 15;
        float a = b_fc1[j2];
        #pragma unroll
        for (int kk = 0; kk < 32; ++kk) a = fmaf(W_fc1[j2*32 + kk], hfin[b][kk], a);
        hd[b][j2] = fmaxf(a, 0.f);
    }
    __syncthreads();
    if (tid < NBB){
        float a = b_fc2[0];
        #pragma unroll
        for (int kk = 0; kk < 16; ++kk) a = fmaf(W_fc2[kk], hd[tid][kk], a);
        out[b0 + tid] = a;
    }
}

extern "C" void kernel_launch(void* const* d_in, const int* in_sizes, int n_in,
                              void* d_out, int out_size, void* d_ws, size_t ws_size,
                              hipStream_t stream) {
    const float* x     = (const float*)d_in[0];
    const float* W_ih1 = (const float*)d_in[1];
    const float* W_hh1 = (const float*)d_in[2];
    const float* b_ih1 = (const float*)d_in[3];
    const float* b_hh1 = (const float*)d_in[4];
    const float* W_ih2 = (const float*)d_in[5];
    const float* W_hh2 = (const float*)d_in[6];
    const float* b_ih2 = (const float*)d_in[7];
    const float* b_hh2 = (const float*)d_in[8];
    const float* W_fc1 = (const float*)d_in[9];
    const float* b_fc1 = (const float*)d_in[10];
    const float* W_fc2 = (const float*)d_in[11];
    const float* b_fc2 = (const float*)d_in[12];
    float* out = (float*)d_out;

    const int B = in_sizes[0] / (T_ * F_);   // 4096
    dim3 grid(B / NBB), block(TPB);          // 256 blocks, 1/CU, 8 waves
    hipLaunchKernelGGL(lstm_mfma, grid, block, 0, stream,
                       x, W_ih1, W_hh1, b_ih1, b_hh1,
                       W_ih2, W_hh2, b_ih2, b_hh2,
                       W_fc1, b_fc1, W_fc2, b_fc2, out);
}